// Round 4
// baseline (305.337 us; speedup 1.0000x reference)
//
#include <hip/hip_runtime.h>

// 3D max pool, kernel=2 stride=2 pad=0.
// Input  [N=2, C=32, D=96, H=96, W=96] fp32
// Output [N=2, C=32, D=48, H=48, W=48] fp32
//
// Non-overlapping windows -> each input element read exactly once.
// Each thread: 4 output floats along W (one float4 store), reading
// 8 float4 (2 per row x 4 rows for the 2x2 (d,h) footprint).

constexpr int IN_W  = 96;
constexpr int IN_HW = 96 * 96;        // 9216
constexpr int IN_DHW = 96 * 96 * 96;  // 884736
constexpr int OUT_W = 48;
constexpr int OUT_HW = 48 * 48;       // 2304
constexpr int OUT_DHW = 48 * 48 * 48; // 110592
constexpr int W4 = OUT_W / 4;         // 12 output-float4 chunks per out row
constexpr int TOTAL_THREADS = 2 * 32 * 48 * 48 * W4; // 1,769,472

__global__ __launch_bounds__(256) void maxpool3d_k2s2(
    const float* __restrict__ in, float* __restrict__ out) {
    int tid = blockIdx.x * blockDim.x + threadIdx.x;
    if (tid >= TOTAL_THREADS) return;

    int ow4 = tid % W4;
    int t1  = tid / W4;
    int oh  = t1 % 48;
    int t2  = t1 / 48;
    int od  = t2 % 48;
    int nc  = t2 / 48;   // fused N*C in [0,64)

    // input base: element (nc, 2*od, 2*oh, 8*ow4); all fits in int32
    int in_base = nc * IN_DHW + (2 * od) * IN_HW + (2 * oh) * IN_W + ow4 * 8;

    const float4* r00 = reinterpret_cast<const float4*>(in + in_base);
    const float4* r01 = reinterpret_cast<const float4*>(in + in_base + IN_W);
    const float4* r10 = reinterpret_cast<const float4*>(in + in_base + IN_HW);
    const float4* r11 = reinterpret_cast<const float4*>(in + in_base + IN_HW + IN_W);

    float4 a0 = r00[0], a1 = r00[1];
    float4 b0 = r01[0], b1 = r01[1];
    float4 c0 = r10[0], c1 = r10[1];
    float4 d0 = r11[0], d1 = r11[1];

    // elementwise max across the 4 (d,h) rows
    float4 m0, m1;
    m0.x = fmaxf(fmaxf(a0.x, b0.x), fmaxf(c0.x, d0.x));
    m0.y = fmaxf(fmaxf(a0.y, b0.y), fmaxf(c0.y, d0.y));
    m0.z = fmaxf(fmaxf(a0.z, b0.z), fmaxf(c0.z, d0.z));
    m0.w = fmaxf(fmaxf(a0.w, b0.w), fmaxf(c0.w, d0.w));
    m1.x = fmaxf(fmaxf(a1.x, b1.x), fmaxf(c1.x, d1.x));
    m1.y = fmaxf(fmaxf(a1.y, b1.y), fmaxf(c1.y, d1.y));
    m1.z = fmaxf(fmaxf(a1.z, b1.z), fmaxf(c1.z, d1.z));
    m1.w = fmaxf(fmaxf(a1.w, b1.w), fmaxf(c1.w, d1.w));

    // pairwise reduce along W: out w = max(in 2w, 2w+1)
    float4 o;
    o.x = fmaxf(m0.x, m0.y);
    o.y = fmaxf(m0.z, m0.w);
    o.z = fmaxf(m1.x, m1.y);
    o.w = fmaxf(m1.z, m1.w);

    int out_idx = nc * OUT_DHW + od * OUT_HW + oh * OUT_W + ow4 * 4;
    *reinterpret_cast<float4*>(out + out_idx) = o;
}

extern "C" void kernel_launch(void* const* d_in, const int* in_sizes, int n_in,
                              void* d_out, int out_size, void* d_ws, size_t ws_size,
                              hipStream_t stream) {
    const float* x = reinterpret_cast<const float*>(d_in[0]);
    float* out = reinterpret_cast<float*>(d_out);
    constexpr int BLOCK = 256;
    constexpr int GRID = (TOTAL_THREADS + BLOCK - 1) / BLOCK; // 6912
    maxpool3d_k2s2<<<GRID, BLOCK, 0, stream>>>(x, out);
}